// Round 4
// baseline (61.098 us; speedup 1.0000x reference)
//
#include <hip/hip_runtime.h>

// Problem constants (must match reference)
constexpr int kBImg   = 16384;
constexpr int kG      = 7;
constexpr int kCh     = 30;          // 5*NB + CLS
constexpr int kT      = kBImg * 8;   // 131072 targets
constexpr int kNCells = kBImg * kG * kG;       // 802,816 cells
constexpr int kThreads    = 256;
constexpr int kCellBlocks = kNCells / kThreads; // 3136 (exact)

__global__ void loss_init(float* __restrict__ outv) {
    outv[0] = 0.f;
}

__global__ __launch_bounds__(kThreads)
void loss_main(const float* __restrict__ outp,
               const float* __restrict__ tgt,
               float* __restrict__ outv) {
    const int tid = blockIdx.x * kThreads + threadIdx.x;   // one thread per cell

    // ---- Phase A: lambda_noobj * c^2, channels 4 and 9 of this thread's cell.
    // Two scattered dword loads; a wave's 64 lanes put ~128 lines in flight,
    // and lines holding no confidence (5 of every 15) are never requested.
    const float* cell = outp + tid * kCh;
    float c4 = cell[4];
    float c9 = cell[9];
    float acc = 0.5f * (c4 * c4 + c9 * c9);   // LAMBDA_NOOBJ = 0.5

    // ---- Phase B: per-target terms (threads 0..kT-1 each own one target).
    // Target row = 8 floats: {x, y, w, h, gx, gy, cls, bid}
    if (tid < kT) {
        const float4* t4 = reinterpret_cast<const float4*>(tgt);
        float4 ta = t4[2 * tid];       // x, y, w, h
        float4 tb = t4[2 * tid + 1];   // gx, gy, cls, bid
        float x_t = ta.x, y_t = ta.y, w_t = ta.z, h_t = ta.w;
        int gx    = (int)tb.x;
        int gy    = (int)tb.y;
        int cls_t = (int)tb.z;
        int bid   = (int)tb.w;
        const float* g = outp + ((bid * kG + gx) * kG + gy) * kCh;

        float top_t   = y_t - 3.5f * h_t, bot_t   = y_t + 3.5f * h_t;
        float left_t  = x_t - 3.5f * w_t, right_t = x_t + 3.5f * w_t;
        float area_t  = w_t * h_t * 49.f;

        // box 0
        float x0 = g[0], y0 = g[1], w0 = g[2], h0 = g[3], c0 = g[4];
        float wi0 = fmaxf(fminf(x0 + 3.5f*w0, right_t) - fmaxf(x0 - 3.5f*w0, left_t), 0.f);
        float hi0 = fmaxf(fmaxf(y0 - 3.5f*h0, top_t)   - fminf(y0 + 3.5f*h0, bot_t), 0.f);
        float ai0 = wi0 * hi0;
        float at0 = area_t + w0 * h0 * 49.f - ai0;
        float iou0 = (at0 > 0.f) ? (ai0 / at0) : 0.f;

        // box 1
        float x1 = g[5], y1 = g[6], w1 = g[7], h1 = g[8], c1 = g[9];
        float wi1 = fmaxf(fminf(x1 + 3.5f*w1, right_t) - fmaxf(x1 - 3.5f*w1, left_t), 0.f);
        float hi1 = fmaxf(fmaxf(y1 - 3.5f*h1, top_t)   - fminf(y1 + 3.5f*h1, bot_t), 0.f);
        float ai1 = wi1 * hi1;
        float at1 = area_t + w1 * h1 * 49.f - ai1;
        float iou1 = (at1 > 0.f) ? (ai1 / at1) : 0.f;

        // argmax with first-max-wins tie rule (jnp.argmax)
        bool pick1 = (iou1 > iou0);
        float x_r = pick1 ? x1 : x0;
        float y_r = pick1 ? y1 : y0;
        float w_r = pick1 ? w1 : w0;
        float h_r = pick1 ? h1 : h0;
        float c_r = pick1 ? c1 : c0;

        float dx = x_t - x_r, dy = y_t - y_r;
        float dw = sqrtf(w_t) - sqrtf(w_r);
        float dh = sqrtf(h_t) - sqrtf(h_r);
        acc += 5.f * (dx*dx + dy*dy + dw*dw + dh*dh);      // LAMBDA_COORD
        acc += (c_r - 1.f) * (c_r - 1.f) - 0.5f * c_r * c_r;

        float s = 0.f;
        #pragma unroll
        for (int k = 0; k < 20; ++k) { float cv = g[10 + k]; s += cv * cv; }
        acc += s;
        float clr = g[10 + cls_t];
        acc += (clr - 1.f) * (clr - 1.f) - clr * clr;
    }

    // ---- Deterministic block reduction, then one atomic per block ----
    __shared__ float sm[kThreads];
    sm[threadIdx.x] = acc;
    __syncthreads();
    for (int s = kThreads / 2; s > 0; s >>= 1) {
        if (threadIdx.x < s) sm[threadIdx.x] += sm[threadIdx.x + s];
        __syncthreads();
    }
    if (threadIdx.x == 0) {
        atomicAdd(outv, sm[0] * (1.f / (float)kBImg));
    }
}

extern "C" void kernel_launch(void* const* d_in, const int* in_sizes, int n_in,
                              void* d_out, int out_size, void* d_ws, size_t ws_size,
                              hipStream_t stream) {
    const float* outp = (const float*)d_in[0];   // (16384,7,7,30) f32
    const float* tgt  = (const float*)d_in[1];   // (131072,8) f32
    float* outv       = (float*)d_out;

    loss_init<<<1, 1, 0, stream>>>(outv);
    loss_main<<<kCellBlocks, kThreads, 0, stream>>>(outp, tgt, outv);
}

// Round 5
// 44.180 us; speedup vs baseline: 1.3829x; 1.3829x over previous
//
#include <hip/hip_runtime.h>

// Problem constants (must match reference)
constexpr int kBImg   = 16384;
constexpr int kG      = 7;
constexpr int kCh     = 30;            // 5*NB + CLS
constexpr int kT      = kBImg * 8;     // 131072 targets
constexpr int kNCells = kBImg * kG * kG;        // 802,816 cells
constexpr int kNF4    = kNCells * kCh / 4;      // 6,021,120 float4s
constexpr int kThreads = 256;
constexpr int kBlocks  = 392;
constexpr int kTotThr  = kBlocks * kThreads;    // 100,352
constexpr int kF4PerThr = kNF4 / kTotThr;       // 60 (exact)
// residue step: (4 * kTotThr) % 30 == 8
static_assert(kF4PerThr * kTotThr == kNF4, "exact cover");

__global__ void loss_init(float* __restrict__ outv) {
    outv[0] = 0.f;
}

__global__ __launch_bounds__(kThreads)
void loss_main(const float* __restrict__ outp,
               const float* __restrict__ tgt,
               float* __restrict__ partial,   // nullptr -> atomic fallback
               float* __restrict__ outv) {
    const int tid = blockIdx.x * kThreads + threadIdx.x;
    float acc = 0.f;

    // ---- Phase A: lambda_noobj * c^2 over channels 4 and 9 of every cell ----
    // Coalesced float4 stream, 60 per thread, deep unroll for MLP.
    // Residue r = (4*i) % 30 selects the confidence lane:
    //   r==2 -> .z (ch4) ; r==4 -> .x (ch4) ; r==6 -> .w (ch9) ; r==8 -> .y (ch9)
    {
        const float4* o4 = reinterpret_cast<const float4*>(outp);
        int i = tid;
        unsigned r = (4u * (unsigned)tid) % 30u;
        #pragma unroll 15
        for (int j = 0; j < kF4PerThr; ++j) {
            float4 v = o4[i];
            float c = (r == 2u) ? v.z
                    : (r == 4u) ? v.x
                    : (r == 6u) ? v.w
                    : (r == 8u) ? v.y : 0.f;
            acc += 0.5f * c * c;   // LAMBDA_NOOBJ = 0.5
            i += kTotThr;
            r += 8u; if (r >= 30u) r -= 30u;
        }
    }

    // ---- Phase B: per-target terms. Target row = 8 floats:
    //      {x, y, w, h, gx, gy, cls, bid}
    const float4* t4 = reinterpret_cast<const float4*>(tgt);
    for (int t = tid; t < kT; t += kTotThr) {
        float4 ta = t4[2 * t];       // x, y, w, h
        float4 tb = t4[2 * t + 1];   // gx, gy, cls, bid
        float x_t = ta.x, y_t = ta.y, w_t = ta.z, h_t = ta.w;
        int gx    = (int)tb.x;
        int gy    = (int)tb.y;
        int cls_t = (int)tb.z;
        int bid   = (int)tb.w;
        const float* g = outp + ((bid * kG + gx) * kG + gy) * kCh;

        float top_t   = y_t - 3.5f * h_t, bot_t   = y_t + 3.5f * h_t;
        float left_t  = x_t - 3.5f * w_t, right_t = x_t + 3.5f * w_t;
        float area_t  = w_t * h_t * 49.f;

        // box 0
        float x0 = g[0], y0 = g[1], w0 = g[2], h0 = g[3], c0 = g[4];
        float wi0 = fmaxf(fminf(x0 + 3.5f*w0, right_t) - fmaxf(x0 - 3.5f*w0, left_t), 0.f);
        float hi0 = fmaxf(fmaxf(y0 - 3.5f*h0, top_t)   - fminf(y0 + 3.5f*h0, bot_t), 0.f);
        float ai0 = wi0 * hi0;
        float at0 = area_t + w0 * h0 * 49.f - ai0;
        float iou0 = (at0 > 0.f) ? (ai0 / at0) : 0.f;

        // box 1
        float x1 = g[5], y1 = g[6], w1 = g[7], h1 = g[8], c1 = g[9];
        float wi1 = fmaxf(fminf(x1 + 3.5f*w1, right_t) - fmaxf(x1 - 3.5f*w1, left_t), 0.f);
        float hi1 = fmaxf(fmaxf(y1 - 3.5f*h1, top_t)   - fminf(y1 + 3.5f*h1, bot_t), 0.f);
        float ai1 = wi1 * hi1;
        float at1 = area_t + w1 * h1 * 49.f - ai1;
        float iou1 = (at1 > 0.f) ? (ai1 / at1) : 0.f;

        // argmax with first-max-wins tie rule (jnp.argmax)
        bool pick1 = (iou1 > iou0);
        float x_r = pick1 ? x1 : x0;
        float y_r = pick1 ? y1 : y0;
        float w_r = pick1 ? w1 : w0;
        float h_r = pick1 ? h1 : h0;
        float c_r = pick1 ? c1 : c0;

        float dx = x_t - x_r, dy = y_t - y_r;
        float dw = sqrtf(w_t) - sqrtf(w_r);
        float dh = sqrtf(h_t) - sqrtf(h_r);
        acc += 5.f * (dx*dx + dy*dy + dw*dw + dh*dh);      // LAMBDA_COORD
        acc += (c_r - 1.f) * (c_r - 1.f) - 0.5f * c_r * c_r;

        float s = 0.f;
        #pragma unroll
        for (int k = 0; k < 20; ++k) { float cv = g[10 + k]; s += cv * cv; }
        acc += s;
        float clr = g[10 + cls_t];
        acc += (clr - 1.f) * (clr - 1.f) - clr * clr;
    }

    // ---- Deterministic block reduction ----
    __shared__ float sm[kThreads];
    sm[threadIdx.x] = acc;
    __syncthreads();
    for (int s = kThreads / 2; s > 0; s >>= 1) {
        if (threadIdx.x < s) sm[threadIdx.x] += sm[threadIdx.x + s];
        __syncthreads();
    }
    if (threadIdx.x == 0) {
        if (partial) {
            partial[blockIdx.x] = sm[0];               // no atomics
        } else {
            atomicAdd(outv, sm[0] * (1.f / (float)kBImg));  // fallback
        }
    }
}

__global__ __launch_bounds__(kThreads)
void loss_reduce(const float* __restrict__ partial, float* __restrict__ outv) {
    __shared__ float sm[kThreads];
    float a = 0.f;
    for (int i = threadIdx.x; i < kBlocks; i += kThreads) a += partial[i];
    sm[threadIdx.x] = a;
    __syncthreads();
    for (int s = kThreads / 2; s > 0; s >>= 1) {
        if (threadIdx.x < s) sm[threadIdx.x] += sm[threadIdx.x + s];
        __syncthreads();
    }
    if (threadIdx.x == 0) outv[0] = sm[0] * (1.f / (float)kBImg);
}

extern "C" void kernel_launch(void* const* d_in, const int* in_sizes, int n_in,
                              void* d_out, int out_size, void* d_ws, size_t ws_size,
                              hipStream_t stream) {
    const float* outp = (const float*)d_in[0];   // (16384,7,7,30) f32
    const float* tgt  = (const float*)d_in[1];   // (131072,8) f32
    float* outv       = (float*)d_out;

    const bool use_ws = (d_ws != nullptr) && (ws_size >= (size_t)kBlocks * sizeof(float));
    float* partial = use_ws ? (float*)d_ws : nullptr;

    if (use_ws) {
        loss_main<<<kBlocks, kThreads, 0, stream>>>(outp, tgt, partial, outv);
        loss_reduce<<<1, kThreads, 0, stream>>>(partial, outv);
    } else {
        loss_init<<<1, 1, 0, stream>>>(outv);
        loss_main<<<kBlocks, kThreads, 0, stream>>>(outp, tgt, nullptr, outv);
    }
}

// Round 6
// 27.075 us; speedup vs baseline: 2.2566x; 1.6317x over previous
//
#include <hip/hip_runtime.h>

// Problem constants (must match reference)
constexpr int kBImg   = 16384;
constexpr int kG      = 7;
constexpr int kCh     = 30;            // 5*NB + CLS
constexpr int kT      = kBImg * 8;     // 131072 targets
constexpr int kNCells = kBImg * kG * kG;   // 802,816 cells
constexpr int kNConf  = 2 * kNCells;       // 1,605,632 confidence dwords
constexpr int kThreads = 256;

// Phase A: one thread handles 16 confidence dwords
constexpr int kBlocksA    = 392;
constexpr int kThrA       = kBlocksA * kThreads;   // 100,352
constexpr int kConfPerThr = kNConf / kThrA;        // 16 (exact)
static_assert(kConfPerThr * kThrA == kNConf, "exact cover");
// per-j dword stride: 30 * (kThrA/2) = 1,505,280
constexpr int kStrideA = kCh * (kThrA / 2);

// Phase B: one thread per target
constexpr int kBlocksB = kT / kThreads;            // 512 (exact)
constexpr int kBlocksTot = kBlocksA + kBlocksB;    // 904

__global__ void loss_init(float* __restrict__ outv) {
    outv[0] = 0.f;
}

__global__ __launch_bounds__(kThreads)
void loss_main(const float* __restrict__ outp,
               const float* __restrict__ tgt,
               float* __restrict__ partial,   // nullptr -> atomic fallback
               float* __restrict__ outv) {
    float acc = 0.f;

    if (blockIdx.x < kBlocksA) {
        // ---- Phase A: lambda_noobj * c^2 over channels 4 and 9 of every cell.
        // Thread t owns confidences n = t + j*kThrA (j=0..15). Since kThrA is
        // even, n&1 is fixed per thread -> fixed channel offset {4 or 9}, and
        // cell = (t>>1) + j*kThrA/2. 16 fully independent dword loads.
        const int tid   = blockIdx.x * kThreads + threadIdx.x;
        const int chOff = (tid & 1) ? 9 : 4;
        const float* p  = outp + kCh * (tid >> 1) + chOff;
        float c[kConfPerThr];
        #pragma unroll
        for (int j = 0; j < kConfPerThr; ++j) c[j] = p[j * kStrideA];
        #pragma unroll
        for (int j = 0; j < kConfPerThr; ++j) acc += 0.5f * c[j] * c[j];
    } else {
        // ---- Phase B: one target per thread.
        // Target row = 8 floats: {x, y, w, h, gx, gy, cls, bid}
        const int btid = (blockIdx.x - kBlocksA) * kThreads + threadIdx.x;
        const float4* t4 = reinterpret_cast<const float4*>(tgt);
        float4 ta = t4[2 * btid];       // x, y, w, h
        float4 tb = t4[2 * btid + 1];   // gx, gy, cls, bid
        float x_t = ta.x, y_t = ta.y, w_t = ta.z, h_t = ta.w;
        int gx    = (int)tb.x;
        int gy    = (int)tb.y;
        int cls_t = (int)tb.z;
        int bid   = (int)tb.w;

        // Cell base: 30 floats = 120 bytes -> always 8B aligned, use float2.
        const float2* gf2 = reinterpret_cast<const float2*>(
            outp + ((bid * kG + gx) * kG + gy) * kCh);

        // 15 independent float2 loads, all statically indexed.
        float2 p0 = gf2[0], p1 = gf2[1], p2 = gf2[2], p3 = gf2[3], p4 = gf2[4];
        float2 q[10];
        #pragma unroll
        for (int jj = 0; jj < 10; ++jj) q[jj] = gf2[5 + jj];

        float x0 = p0.x, y0 = p0.y, w0 = p1.x, h0 = p1.y, c0 = p2.x;
        float x1 = p2.y, y1 = p3.x, w1 = p3.y, h1 = p4.x, c1 = p4.y;

        float top_t   = y_t - 3.5f * h_t, bot_t   = y_t + 3.5f * h_t;
        float left_t  = x_t - 3.5f * w_t, right_t = x_t + 3.5f * w_t;
        float area_t  = w_t * h_t * 49.f;

        // box 0
        float wi0 = fmaxf(fminf(x0 + 3.5f*w0, right_t) - fmaxf(x0 - 3.5f*w0, left_t), 0.f);
        float hi0 = fmaxf(fmaxf(y0 - 3.5f*h0, top_t)   - fminf(y0 + 3.5f*h0, bot_t), 0.f);
        float ai0 = wi0 * hi0;
        float at0 = area_t + w0 * h0 * 49.f - ai0;
        float iou0 = (at0 > 0.f) ? (ai0 / at0) : 0.f;

        // box 1
        float wi1 = fmaxf(fminf(x1 + 3.5f*w1, right_t) - fmaxf(x1 - 3.5f*w1, left_t), 0.f);
        float hi1 = fmaxf(fmaxf(y1 - 3.5f*h1, top_t)   - fminf(y1 + 3.5f*h1, bot_t), 0.f);
        float ai1 = wi1 * hi1;
        float at1 = area_t + w1 * h1 * 49.f - ai1;
        float iou1 = (at1 > 0.f) ? (ai1 / at1) : 0.f;

        // argmax with first-max-wins tie rule (jnp.argmax)
        bool pick1 = (iou1 > iou0);
        float x_r = pick1 ? x1 : x0;
        float y_r = pick1 ? y1 : y0;
        float w_r = pick1 ? w1 : w0;
        float h_r = pick1 ? h1 : h0;
        float c_r = pick1 ? c1 : c0;

        float dx = x_t - x_r, dy = y_t - y_r;
        float dw = sqrtf(w_t) - sqrtf(w_r);
        float dh = sqrtf(h_t) - sqrtf(h_r);
        acc += 5.f * (dx*dx + dy*dy + dw*dw + dh*dh);      // LAMBDA_COORD
        acc += (c_r - 1.f) * (c_r - 1.f) - 0.5f * c_r * c_r;

        // class terms: sum of squares + gathered class, all static indices
        float s = 0.f, clr = 0.f;
        #pragma unroll
        for (int jj = 0; jj < 10; ++jj) {
            s += q[jj].x * q[jj].x + q[jj].y * q[jj].y;
            clr = (cls_t == 2 * jj)     ? q[jj].x : clr;
            clr = (cls_t == 2 * jj + 1) ? q[jj].y : clr;
        }
        acc += s;
        acc += (clr - 1.f) * (clr - 1.f) - clr * clr;
    }

    // ---- Deterministic block reduction ----
    __shared__ float sm[kThreads];
    sm[threadIdx.x] = acc;
    __syncthreads();
    for (int s = kThreads / 2; s > 0; s >>= 1) {
        if (threadIdx.x < s) sm[threadIdx.x] += sm[threadIdx.x + s];
        __syncthreads();
    }
    if (threadIdx.x == 0) {
        if (partial) {
            partial[blockIdx.x] = sm[0];               // no atomics
        } else {
            atomicAdd(outv, sm[0] * (1.f / (float)kBImg));  // fallback
        }
    }
}

__global__ __launch_bounds__(kThreads)
void loss_reduce(const float* __restrict__ partial, float* __restrict__ outv) {
    __shared__ float sm[kThreads];
    float a = 0.f;
    for (int i = threadIdx.x; i < kBlocksTot; i += kThreads) a += partial[i];
    sm[threadIdx.x] = a;
    __syncthreads();
    for (int s = kThreads / 2; s > 0; s >>= 1) {
        if (threadIdx.x < s) sm[threadIdx.x] += sm[threadIdx.x + s];
        __syncthreads();
    }
    if (threadIdx.x == 0) outv[0] = sm[0] * (1.f / (float)kBImg);
}

extern "C" void kernel_launch(void* const* d_in, const int* in_sizes, int n_in,
                              void* d_out, int out_size, void* d_ws, size_t ws_size,
                              hipStream_t stream) {
    const float* outp = (const float*)d_in[0];   // (16384,7,7,30) f32
    const float* tgt  = (const float*)d_in[1];   // (131072,8) f32
    float* outv       = (float*)d_out;

    const bool use_ws = (d_ws != nullptr) && (ws_size >= (size_t)kBlocksTot * sizeof(float));
    float* partial = use_ws ? (float*)d_ws : nullptr;

    if (use_ws) {
        loss_main<<<kBlocksTot, kThreads, 0, stream>>>(outp, tgt, partial, outv);
        loss_reduce<<<1, kThreads, 0, stream>>>(partial, outv);
    } else {
        loss_init<<<1, 1, 0, stream>>>(outv);
        loss_main<<<kBlocksTot, kThreads, 0, stream>>>(outp, tgt, nullptr, outv);
    }
}